// Round 3
// baseline (4168.409 us; speedup 1.0000x reference)
//
#include <hip/hip_runtime.h>

typedef __bf16 bf16_t;
typedef __bf16 bf16x8 __attribute__((ext_vector_type(8)));
typedef float floatx4 __attribute__((ext_vector_type(4)));

static constexpr int NB = 4, NS = 2048, ND = 1024, NH = 8, NHID = 4096;
static constexpr int NTOK = NB * NS;  // 8192
static constexpr int HG = 2;          // heads per group

__device__ __forceinline__ void async_copy16(const void* g, void* l) {
  __builtin_amdgcn_global_load_lds(
      (const __attribute__((address_space(1))) void*)g,
      (__attribute__((address_space(3))) void*)l, 16, 0, 0);
}

// C[m][n] = alpha * sum_k A[m][k] * Bt[n][k]  (+bias[n]) (opt relu)
// accum: C[m][n] += alpha * (...)   (fp32 C only; bias ignored)
// A, Bt bf16 row-major; C fp32 or bf16; optional transposed store (C[n][m]).
// Tiles: 128x128, BK=64, 256 threads (4 waves, 2x2 of 64x64 each).
// Per-z offsets: off = (z/zi)*so + (z%zi)*si   (elements).
template <bool OUT_BF16, bool TRANS_C>
__global__ __launch_bounds__(256, 3) void gemm_bt(
    const bf16_t* __restrict__ A, int lda, const bf16_t* __restrict__ Bt,
    int ldb, void* __restrict__ Cv, int ldc, int K, float alpha,
    const float* __restrict__ bias, int do_relu, int accum, int zi,
    long long a_so, long long a_si, long long b_so, long long b_si,
    long long c_so, long long c_si) {
  const int z = blockIdx.z;
  const int zo = z / zi, zr = z % zi;
  A += zo * a_so + zr * a_si;
  Bt += zo * b_so + zr * b_si;
  const long long c_off = zo * c_so + zr * c_si;

  const int tn = blockIdx.x * 128;
  const int tm = blockIdx.y * 128;

  __shared__ alignas(16) bf16_t As[128 * 64];
  __shared__ alignas(16) bf16_t Bs[128 * 64];

  const int tid = threadIdx.x;
  const int wave = tid >> 6;
  const int lane = tid & 63;
  const int wm = wave >> 1, wn = wave & 1;
  const int r = lane & 15, quad = lane >> 4;
  const int g = lane >> 3, p = lane & 7;
  const int swz = p ^ g;  // XOR swizzle at 16B-chunk granularity

  floatx4 acc[4][4];
#pragma unroll
  for (int i = 0; i < 4; ++i)
#pragma unroll
    for (int j = 0; j < 4; ++j) acc[i][j] = floatx4{0.f, 0.f, 0.f, 0.f};

  // staging: wave handles rows [wave*32, wave*32+32); lane covers row g of
  // each 8-row chunk, 16B chunk (p ^ row&7) of the 128B row.
  const int srow = wave * 32 + g;
  const bf16_t* agp = A + (long long)(tm + srow) * lda + swz * 8;
  const bf16_t* bgp = Bt + (long long)(tn + srow) * ldb + swz * 8;
  bf16_t* ald = &As[(wave * 32) * 64];
  bf16_t* bld = &Bs[(wave * 32) * 64];

  for (int k0 = 0; k0 < K; k0 += 64) {
    __syncthreads();
#pragma unroll
    for (int c = 0; c < 4; ++c) {
      async_copy16(agp + (long long)(c * 8) * lda + k0, ald + c * 8 * 64);
      async_copy16(bgp + (long long)(c * 8) * ldb + k0, bld + c * 8 * 64);
    }
    __syncthreads();
#pragma unroll
    for (int t = 0; t < 2; ++t) {
      bf16x8 af[4], bfv[4];
      const int ca = (t * 4 + quad) ^ (r & 7);
#pragma unroll
      for (int i = 0; i < 4; ++i) {
        const int m = wm * 64 + i * 16 + r;
        af[i] = *(const bf16x8*)&As[m * 64 + ca * 8];
        const int n = wn * 64 + i * 16 + r;
        bfv[i] = *(const bf16x8*)&Bs[n * 64 + ca * 8];
      }
#pragma unroll
      for (int i = 0; i < 4; ++i)
#pragma unroll
        for (int j = 0; j < 4; ++j)
          acc[i][j] = __builtin_amdgcn_mfma_f32_16x16x32_bf16(af[i], bfv[j],
                                                              acc[i][j], 0, 0, 0);
    }
  }

  // epilogue: D[row][col], row = quad*4+reg, col = r (per 16x16 block)
  const int cm = tm + wm * 64;
  const int cn = tn + wn * 64;
#pragma unroll
  for (int j = 0; j < 4; ++j) {
    const int col = cn + j * 16 + r;
    const float bv = (bias && !accum) ? bias[col] : 0.0f;
#pragma unroll
    for (int i = 0; i < 4; ++i) {
      const int row0 = cm + i * 16 + quad * 4;
#pragma unroll
      for (int rg = 0; rg < 4; ++rg) {
        float v = acc[i][j][rg] * alpha + bv;
        if (do_relu) v = fmaxf(v, 0.0f);
        long long idx;
        if (TRANS_C)
          idx = c_off + (long long)col * ldc + (row0 + rg);
        else
          idx = c_off + (long long)(row0 + rg) * ldc + col;
        if (OUT_BF16) {
          ((bf16_t*)Cv)[idx] = (bf16_t)v;
        } else {
          float* cp = (float*)Cv + idx;
          *cp = accum ? (*cp + v) : v;
        }
      }
    }
  }
}

// out[c][r] = (bf16) in[r][c], per z-slice
__global__ __launch_bounds__(256) void transpose_to_bf16(
    const float* __restrict__ in, bf16_t* __restrict__ out, int R, int C,
    long long in_zs, long long out_zs) {
  __shared__ float tile[32][33];
  in += (long long)blockIdx.z * in_zs;
  out += (long long)blockIdx.z * out_zs;
  const int tx = threadIdx.x & 31, ty = threadIdx.x >> 5;
  const int r0 = blockIdx.y * 32, c0 = blockIdx.x * 32;
#pragma unroll
  for (int d = 0; d < 32; d += 8)
    tile[ty + d][tx] = in[(long long)(r0 + ty + d) * C + c0 + tx];
  __syncthreads();
#pragma unroll
  for (int d = 0; d < 32; d += 8)
    out[(long long)(c0 + ty + d) * R + r0 + tx] = (bf16_t)tile[tx][ty + d];
}

__global__ __launch_bounds__(256) void f32_to_bf16(const float* __restrict__ in,
                                                   bf16_t* __restrict__ out,
                                                   long long n) {
  long long i = (long long)blockIdx.x * 1024 + threadIdx.x * 4;
  const long long stride = (long long)gridDim.x * 1024;
  for (; i < n; i += stride) {
    float4 v = *(const float4*)(in + i);
    out[i] = (bf16_t)v.x;
    out[i + 1] = (bf16_t)v.y;
    out[i + 2] = (bf16_t)v.z;
    out[i + 3] = (bf16_t)v.w;
  }
}

// in-place softmax over rows of 2048 bf16; one 256-thread block per row
__global__ __launch_bounds__(256) void softmax2048(bf16_t* __restrict__ pbuf) {
  __shared__ float redm[4], reds[4];
  bf16_t* pr = pbuf + (long long)blockIdx.x * 2048;
  bf16x8 raw = *(bf16x8*)(pr + threadIdx.x * 8);
  float v[8];
  float mx = -1e30f;
#pragma unroll
  for (int j = 0; j < 8; ++j) {
    v[j] = (float)raw[j];
    mx = fmaxf(mx, v[j]);
  }
#pragma unroll
  for (int o = 32; o > 0; o >>= 1) mx = fmaxf(mx, __shfl_down(mx, o, 64));
  if ((threadIdx.x & 63) == 0) redm[threadIdx.x >> 6] = mx;
  __syncthreads();
  mx = fmaxf(fmaxf(redm[0], redm[1]), fmaxf(redm[2], redm[3]));
  float s = 0.f;
#pragma unroll
  for (int j = 0; j < 8; ++j) {
    v[j] = __expf(v[j] - mx);
    s += v[j];
  }
#pragma unroll
  for (int o = 32; o > 0; o >>= 1) s += __shfl_down(s, o, 64);
  if ((threadIdx.x & 63) == 0) reds[threadIdx.x >> 6] = s;
  __syncthreads();
  s = reds[0] + reds[1] + reds[2] + reds[3];
  const float inv = 1.0f / s;
  bf16x8 o8;
#pragma unroll
  for (int j = 0; j < 8; ++j) o8[j] = (bf16_t)(v[j] * inv);
  *(bf16x8*)(pr + threadIdx.x * 8) = o8;
}

// out = LN(a + res) * gamma + beta. res from resf (fp32) if non-null else resb
// (bf16). Writes outf (fp32) and/or outb (bf16). D = 1024 fixed.
__global__ __launch_bounds__(256) void add_res_ln(
    const float* __restrict__ a, const float* __restrict__ resf,
    const bf16_t* __restrict__ resb, const float* __restrict__ gamma,
    const float* __restrict__ beta, float* __restrict__ outf,
    bf16_t* __restrict__ outb) {
  __shared__ float rs[4], rq[4];
  const long long row = blockIdx.x;
  const int t = threadIdx.x;
  float4 av = *(const float4*)(a + row * 1024 + t * 4);
  float r0, r1, r2, r3;
  if (resf) {
    float4 rv = *(const float4*)(resf + row * 1024 + t * 4);
    r0 = rv.x; r1 = rv.y; r2 = rv.z; r3 = rv.w;
  } else {
    const bf16_t* rb = resb + row * 1024 + t * 4;
    r0 = (float)rb[0]; r1 = (float)rb[1]; r2 = (float)rb[2]; r3 = (float)rb[3];
  }
  const float x0 = av.x + r0, x1 = av.y + r1, x2 = av.z + r2, x3 = av.w + r3;
  float s = x0 + x1 + x2 + x3;
  float q = x0 * x0 + x1 * x1 + x2 * x2 + x3 * x3;
#pragma unroll
  for (int o = 32; o > 0; o >>= 1) {
    s += __shfl_down(s, o, 64);
    q += __shfl_down(q, o, 64);
  }
  if ((t & 63) == 0) {
    rs[t >> 6] = s;
    rq[t >> 6] = q;
  }
  __syncthreads();
  s = rs[0] + rs[1] + rs[2] + rs[3];
  q = rq[0] + rq[1] + rq[2] + rq[3];
  const float mean = s * (1.0f / 1024.0f);
  const float var = q * (1.0f / 1024.0f) - mean * mean;
  const float inv = rsqrtf(var + 1e-5f);
  float4 gv = *(const float4*)(gamma + t * 4);
  float4 bv = *(const float4*)(beta + t * 4);
  const float o0 = (x0 - mean) * inv * gv.x + bv.x;
  const float o1 = (x1 - mean) * inv * gv.y + bv.y;
  const float o2 = (x2 - mean) * inv * gv.z + bv.z;
  const float o3 = (x3 - mean) * inv * gv.w + bv.w;
  if (outf) *(float4*)(outf + row * 1024 + t * 4) = make_float4(o0, o1, o2, o3);
  if (outb) {
    bf16_t* ob = outb + row * 1024 + t * 4;
    ob[0] = (bf16_t)o0;
    ob[1] = (bf16_t)o1;
    ob[2] = (bf16_t)o2;
    ob[3] = (bf16_t)o3;
  }
}

extern "C" void kernel_launch(void* const* d_in, const int* in_sizes, int n_in,
                              void* d_out, int out_size, void* d_ws,
                              size_t ws_size, hipStream_t stream) {
  (void)in_sizes;
  (void)n_in;
  (void)out_size;
  (void)ws_size;
  const float* x = (const float*)d_in[0];
  const float* Wq = (const float*)d_in[1];
  const float* Wk = (const float*)d_in[2];
  const float* Wv = (const float*)d_in[3];
  const float* Wo = (const float*)d_in[4];
  const float* bo = (const float*)d_in[5];
  const float* w1 = (const float*)d_in[6];
  const float* b1 = (const float*)d_in[7];
  const float* w2 = (const float*)d_in[8];
  const float* b2 = (const float*)d_in[9];
  const float* w3 = (const float*)d_in[10];
  const float* b3 = (const float*)d_in[11];
  const float* w4 = (const float*)d_in[12];
  const float* b4 = (const float*)d_in[13];
  const float* g1 = (const float*)d_in[14];
  const float* be1 = (const float*)d_in[15];
  const float* g2 = (const float*)d_in[16];
  const float* be2 = (const float*)d_in[17];
  float* out = (float*)d_out;

  const size_t MB = 1024ull * 1024ull;
  char* base = (char*)d_ws;

  // ---- static arena, hard 128 MB peak ----
  // attention phase:
  bf16_t* xb = (bf16_t*)(base + 0 * MB);        // 16 MB, [0,16)
  bf16_t* zbuf = (bf16_t*)(base + 16 * MB);     // 16 MB, [16,32)
  float* attnproj = (float*)(base + 32 * MB);   // 32 MB, [32,64)
  bf16_t* WqTg = (bf16_t*)(base + 64 * MB);     // 4 MB  (HG heads)
  bf16_t* WkTg = (bf16_t*)(base + 68 * MB);     // 4 MB
  bf16_t* WvTg = (bf16_t*)(base + 72 * MB);     // 4 MB
  bf16_t* WoTg = (bf16_t*)(base + 76 * MB);     // 4 MB (1024 x HG*1024)
  bf16_t* qs = (bf16_t*)(base + 80 * MB);       // 8 MB
  bf16_t* ks = (bf16_t*)(base + 88 * MB);       // 8 MB
  bf16_t* vts = (bf16_t*)(base + 96 * MB);      // 8 MB
  bf16_t* scs = (bf16_t*)(base + 104 * MB);     // 16 MB, [104,120)
  bf16_t* zc = (bf16_t*)(base + 120 * MB);      // 8 MB, [120,128)
  // FFN phase (aliases attention regions; zbuf + attnproj->y4 stay):
  float* y4 = (float*)(base + 32 * MB);         // 32 MB (attnproj dead)
  bf16_t* w1T = (bf16_t*)(base + 64 * MB);      // 8 MB, [64,72)
  bf16_t* w4T = (bf16_t*)(base + 72 * MB);      // 8 MB, [72,80)
  bf16_t* w23T = (bf16_t*)(base + 80 * MB);     // 32 MB slot, [80,112)
  bf16_t* y1c = (bf16_t*)(base + 112 * MB);     // 16 MB, [112,128)  (y3c too)
  bf16_t* y2c = (bf16_t*)(base + 0 * MB);       // 16 MB, [0,16)  (xb dead)

  // ---- prep: x -> bf16 ----
  f32_to_bf16<<<dim3(2048), dim3(256), 0, stream>>>(x, xb,
                                                    (long long)NTOK * ND);

  // ---- attention: head-group outer, batch inner; Wo accumulated ----
  for (int g0 = 0; g0 < NH; g0 += HG) {
    transpose_to_bf16<<<dim3(32, 32, HG), dim3(256), 0, stream>>>(
        Wq + (long long)g0 * ND * ND, WqTg, ND, ND, (long long)ND * ND,
        (long long)ND * ND);
    transpose_to_bf16<<<dim3(32, 32, HG), dim3(256), 0, stream>>>(
        Wk + (long long)g0 * ND * ND, WkTg, ND, ND, (long long)ND * ND,
        (long long)ND * ND);
    transpose_to_bf16<<<dim3(32, 32, HG), dim3(256), 0, stream>>>(
        Wv + (long long)g0 * ND * ND, WvTg, ND, ND, (long long)ND * ND,
        (long long)ND * ND);
    // Wo rows [g0*1024, (g0+HG)*1024) -> WoTg [1024][HG*1024]
    transpose_to_bf16<<<dim3(32, HG * 32, 1), dim3(256), 0, stream>>>(
        Wo + (long long)g0 * ND * ND, WoTg, HG * ND, ND, 0, 0);

    for (int bi = 0; bi < NB; ++bi) {
      const bf16_t* xbb = xb + (long long)bi * NS * ND;
      // Q/K/V: M=2048, N=1024, K=1024, z = head in group
      gemm_bt<true, false><<<dim3(8, 16, HG), dim3(256), 0, stream>>>(
          xbb, ND, WqTg, ND, qs, ND, ND, 1.0f, nullptr, 0, 0, HG, 0LL, 0LL,
          0LL, (long long)ND * ND, 0LL, (long long)NS * ND);
      gemm_bt<true, false><<<dim3(8, 16, HG), dim3(256), 0, stream>>>(
          xbb, ND, WkTg, ND, ks, ND, ND, 1.0f, nullptr, 0, 0, HG, 0LL, 0LL,
          0LL, (long long)ND * ND, 0LL, (long long)NS * ND);
      gemm_bt<true, true><<<dim3(8, 16, HG), dim3(256), 0, stream>>>(
          xbb, ND, WvTg, ND, vts, NS, ND, 1.0f, nullptr, 0, 0, HG, 0LL, 0LL,
          0LL, (long long)ND * ND, 0LL, (long long)ND * NS);
      // scores = q k^T / 32 : M=N=2048, K=1024
      gemm_bt<true, false><<<dim3(16, 16, HG), dim3(256), 0, stream>>>(
          qs, ND, ks, ND, scs, NS, ND, 0.03125f, nullptr, 0, 0, HG, 0LL,
          (long long)NS * ND, 0LL, (long long)NS * ND, 0LL,
          (long long)NS * NS);
      softmax2048<<<dim3(HG * NS), dim3(256), 0, stream>>>(scs);
      // zc[s][h*D+e] = P V : M=2048, N=1024, K=2048
      gemm_bt<true, false><<<dim3(8, 16, HG), dim3(256), 0, stream>>>(
          scs, NS, vts, NS, zc, HG * ND, NS, 1.0f, nullptr, 0, 0, HG, 0LL,
          (long long)NS * NS, 0LL, (long long)ND * NS, 0LL, (long long)ND);
      // attnproj[bi] (+)= zc @ WoTg^T : M=2048, N=1024, K=HG*1024
      gemm_bt<false, false><<<dim3(8, 16, 1), dim3(256), 0, stream>>>(
          zc, HG * ND, WoTg, HG * ND, attnproj + (long long)bi * NS * ND, ND,
          HG * ND, 1.0f, bo, 0, (g0 > 0) ? 1 : 0, 1, 0LL, 0LL, 0LL, 0LL, 0LL,
          0LL);
    }
  }

  // z = LN(x + attnproj)  (bf16 only)
  add_res_ln<<<dim3(NTOK), dim3(256), 0, stream>>>(attnproj, x, nullptr, g1,
                                                   be1, nullptr, zbuf);

  // ---- FFN, chunked over tokens (4 x 2048 rows) ----
  transpose_to_bf16<<<dim3(128, 32, 1), dim3(256), 0, stream>>>(w1, w1T, ND,
                                                                NHID, 0, 0);
  transpose_to_bf16<<<dim3(32, 128, 1), dim3(256), 0, stream>>>(w4, w4T, NHID,
                                                                ND, 0, 0);
  for (int c = 0; c < 4; ++c) {
    const bf16_t* zrow = zbuf + (long long)c * NS * ND;
    // y1c = relu(z w1 + b1) : M=2048, N=4096, K=1024
    gemm_bt<true, false><<<dim3(32, 16, 1), dim3(256), 0, stream>>>(
        zrow, ND, w1T, ND, y1c, NHID, ND, 1.0f, b1, 1, 0, 1, 0LL, 0LL, 0LL,
        0LL, 0LL, 0LL);
    transpose_to_bf16<<<dim3(128, 128, 1), dim3(256), 0, stream>>>(
        w2, w23T, NHID, NHID, 0, 0);
    // y2c = relu(y1c w2 + b2) : K=4096
    gemm_bt<true, false><<<dim3(32, 16, 1), dim3(256), 0, stream>>>(
        y1c, NHID, w23T, NHID, y2c, NHID, NHID, 1.0f, b2, 1, 0, 1, 0LL, 0LL,
        0LL, 0LL, 0LL, 0LL);
    transpose_to_bf16<<<dim3(128, 128, 1), dim3(256), 0, stream>>>(
        w3, w23T, NHID, NHID, 0, 0);
    // y3c = relu(y2c w3 + b3) : K=4096 (y3c aliases y1c)
    gemm_bt<true, false><<<dim3(32, 16, 1), dim3(256), 0, stream>>>(
        y2c, NHID, w23T, NHID, y1c, NHID, NHID, 1.0f, b3, 1, 0, 1, 0LL, 0LL,
        0LL, 0LL, 0LL, 0LL);
    // y4 = y3c w4 + b4 : N=1024, K=4096, fp32 out
    gemm_bt<false, false><<<dim3(8, 16, 1), dim3(256), 0, stream>>>(
        y1c, NHID, w4T, NHID, y4 + (long long)c * NS * ND, ND, NHID, 1.0f, b4,
        0, 0, 1, 0LL, 0LL, 0LL, 0LL, 0LL, 0LL);
  }

  // out = LN(z + y4)
  add_res_ln<<<dim3(NTOK), dim3(256), 0, stream>>>(y4, nullptr, zbuf, g2, be2,
                                                   out, nullptr);
}

// Round 4
// 2847.267 us; speedup vs baseline: 1.4640x; 1.4640x over previous
//
#include <hip/hip_runtime.h>

typedef __bf16 bf16_t;
typedef __bf16 bf16x8 __attribute__((ext_vector_type(8)));
typedef __bf16 bf16x4 __attribute__((ext_vector_type(4)));
typedef float floatx4 __attribute__((ext_vector_type(4)));

static constexpr int NB = 4, NS = 2048, ND = 1024, NH = 8, NHID = 4096;
static constexpr int NTOK = NB * NS;  // 8192

__device__ __forceinline__ void async_copy16(const void* g, void* l) {
  __builtin_amdgcn_global_load_lds(
      (const __attribute__((address_space(1))) void*)g,
      (__attribute__((address_space(3))) void*)l, 16, 0, 0);
}

// C[m][n] = alpha * sum_k A[m][k] * Bt[n][k]  (+bias[n]) (opt relu)
// accum: C[m][n] += alpha * (...)   (bias ignored; works for fp32 and bf16 C)
// A, Bt bf16 row-major; C fp32 or bf16; optional transposed store (C[n][m]).
// Tiles: 128x128, BK=64, 256 threads (4 waves, 2x2 of 64x64 each).
// Per-z offsets: off = (z/zi)*so + (z%zi)*si   (elements).
template <bool OUT_BF16, bool TRANS_C>
__global__ __launch_bounds__(256, 3) void gemm_bt(
    const bf16_t* __restrict__ A, int lda, const bf16_t* __restrict__ Bt,
    int ldb, void* __restrict__ Cv, int ldc, int K, float alpha,
    const float* __restrict__ bias, int do_relu, int accum, int zi,
    long long a_so, long long a_si, long long b_so, long long b_si,
    long long c_so, long long c_si) {
  const int z = blockIdx.z;
  const int zo = z / zi, zr = z % zi;
  A += zo * a_so + zr * a_si;
  Bt += zo * b_so + zr * b_si;
  const long long c_off = zo * c_so + zr * c_si;

  const int tn = blockIdx.x * 128;
  const int tm = blockIdx.y * 128;

  __shared__ alignas(16) bf16_t As[128 * 64];
  __shared__ alignas(16) bf16_t Bs[128 * 64];

  const int tid = threadIdx.x;
  const int wave = tid >> 6;
  const int lane = tid & 63;
  const int wm = wave >> 1, wn = wave & 1;
  const int r = lane & 15, quad = lane >> 4;
  const int g = lane >> 3, p = lane & 7;
  const int swz = p ^ g;  // XOR swizzle at 16B-chunk granularity

  floatx4 acc[4][4];
#pragma unroll
  for (int i = 0; i < 4; ++i)
#pragma unroll
    for (int j = 0; j < 4; ++j) acc[i][j] = floatx4{0.f, 0.f, 0.f, 0.f};

  // staging: wave handles rows [wave*32, wave*32+32); lane covers row g of
  // each 8-row chunk, 16B chunk (p ^ row&7) of the 128B row.
  const int srow = wave * 32 + g;
  const bf16_t* agp = A + (long long)(tm + srow) * lda + swz * 8;
  const bf16_t* bgp = Bt + (long long)(tn + srow) * ldb + swz * 8;
  bf16_t* ald = &As[(wave * 32) * 64];
  bf16_t* bld = &Bs[(wave * 32) * 64];

  for (int k0 = 0; k0 < K; k0 += 64) {
    __syncthreads();
#pragma unroll
    for (int c = 0; c < 4; ++c) {
      async_copy16(agp + (long long)(c * 8) * lda + k0, ald + c * 8 * 64);
      async_copy16(bgp + (long long)(c * 8) * ldb + k0, bld + c * 8 * 64);
    }
    __syncthreads();
#pragma unroll
    for (int t = 0; t < 2; ++t) {
      bf16x8 af[4], bfv[4];
      const int ca = (t * 4 + quad) ^ (r & 7);
#pragma unroll
      for (int i = 0; i < 4; ++i) {
        const int m = wm * 64 + i * 16 + r;
        af[i] = *(const bf16x8*)&As[m * 64 + ca * 8];
        const int n = wn * 64 + i * 16 + r;
        bfv[i] = *(const bf16x8*)&Bs[n * 64 + ca * 8];
      }
#pragma unroll
      for (int i = 0; i < 4; ++i)
#pragma unroll
        for (int j = 0; j < 4; ++j)
          acc[i][j] = __builtin_amdgcn_mfma_f32_16x16x32_bf16(af[i], bfv[j],
                                                              acc[i][j], 0, 0, 0);
    }
  }

  // epilogue: D[row][col], row = quad*4+reg, col = r (per 16x16 block)
  const int cm = tm + wm * 64;
  const int cn = tn + wn * 64;
#pragma unroll
  for (int j = 0; j < 4; ++j) {
    const int col = cn + j * 16 + r;
    const float bv = (bias && !accum) ? bias[col] : 0.0f;
#pragma unroll
    for (int i = 0; i < 4; ++i) {
      const int row0 = cm + i * 16 + quad * 4;
#pragma unroll
      for (int rg = 0; rg < 4; ++rg) {
        float v = acc[i][j][rg] * alpha + bv;
        if (do_relu) v = fmaxf(v, 0.0f);
        long long idx;
        if (TRANS_C)
          idx = c_off + (long long)col * ldc + (row0 + rg);
        else
          idx = c_off + (long long)(row0 + rg) * ldc + col;
        if (OUT_BF16) {
          bf16_t* cp = (bf16_t*)Cv + idx;
          const float prev = accum ? (float)*cp : 0.0f;
          *cp = (bf16_t)(prev + v);
        } else {
          float* cp = (float*)Cv + idx;
          *cp = accum ? (*cp + v) : v;
        }
      }
    }
  }
}

// out[c][r] = (bf16) in[r][c], per z-slice
__global__ __launch_bounds__(256) void transpose_to_bf16(
    const float* __restrict__ in, bf16_t* __restrict__ out, int R, int C,
    long long in_zs, long long out_zs) {
  __shared__ float tile[32][33];
  in += (long long)blockIdx.z * in_zs;
  out += (long long)blockIdx.z * out_zs;
  const int tx = threadIdx.x & 31, ty = threadIdx.x >> 5;
  const int r0 = blockIdx.y * 32, c0 = blockIdx.x * 32;
#pragma unroll
  for (int d = 0; d < 32; d += 8)
    tile[ty + d][tx] = in[(long long)(r0 + ty + d) * C + c0 + tx];
  __syncthreads();
#pragma unroll
  for (int d = 0; d < 32; d += 8)
    out[(long long)(c0 + ty + d) * R + r0 + tx] = (bf16_t)tile[tx][ty + d];
}

__global__ __launch_bounds__(256) void f32_to_bf16(const float* __restrict__ in,
                                                   bf16_t* __restrict__ out,
                                                   long long n) {
  long long i = (long long)blockIdx.x * 1024 + threadIdx.x * 4;
  const long long stride = (long long)gridDim.x * 1024;
  for (; i < n; i += stride) {
    float4 v = *(const float4*)(in + i);
    out[i] = (bf16_t)v.x;
    out[i + 1] = (bf16_t)v.y;
    out[i + 2] = (bf16_t)v.z;
    out[i + 3] = (bf16_t)v.w;
  }
}

// in-place softmax over rows of 2048 bf16; one 256-thread block per row
__global__ __launch_bounds__(256) void softmax2048(bf16_t* __restrict__ pbuf) {
  __shared__ float redm[4], reds[4];
  bf16_t* pr = pbuf + (long long)blockIdx.x * 2048;
  bf16x8 raw = *(bf16x8*)(pr + threadIdx.x * 8);
  float v[8];
  float mx = -1e30f;
#pragma unroll
  for (int j = 0; j < 8; ++j) {
    v[j] = (float)raw[j];
    mx = fmaxf(mx, v[j]);
  }
#pragma unroll
  for (int o = 32; o > 0; o >>= 1) mx = fmaxf(mx, __shfl_down(mx, o, 64));
  if ((threadIdx.x & 63) == 0) redm[threadIdx.x >> 6] = mx;
  __syncthreads();
  mx = fmaxf(fmaxf(redm[0], redm[1]), fmaxf(redm[2], redm[3]));
  float s = 0.f;
#pragma unroll
  for (int j = 0; j < 8; ++j) {
    v[j] = __expf(v[j] - mx);
    s += v[j];
  }
#pragma unroll
  for (int o = 32; o > 0; o >>= 1) s += __shfl_down(s, o, 64);
  if ((threadIdx.x & 63) == 0) reds[threadIdx.x >> 6] = s;
  __syncthreads();
  s = reds[0] + reds[1] + reds[2] + reds[3];
  const float inv = 1.0f / s;
  bf16x8 o8;
#pragma unroll
  for (int j = 0; j < 8; ++j) o8[j] = (bf16_t)(v[j] * inv);
  *(bf16x8*)(pr + threadIdx.x * 8) = o8;
}

// out = LN(a + res) * gamma + beta. a is bf16. res from resf (fp32) if
// non-null else resb (bf16). Writes outf (fp32) and/or outb (bf16). D=1024.
__global__ __launch_bounds__(256) void add_res_ln(
    const bf16_t* __restrict__ a, const float* __restrict__ resf,
    const bf16_t* __restrict__ resb, const float* __restrict__ gamma,
    const float* __restrict__ beta, float* __restrict__ outf,
    bf16_t* __restrict__ outb) {
  __shared__ float rs[4], rq[4];
  const long long row = blockIdx.x;
  const int t = threadIdx.x;
  bf16x4 av = *(const bf16x4*)(a + row * 1024 + t * 4);
  float r0, r1, r2, r3;
  if (resf) {
    float4 rv = *(const float4*)(resf + row * 1024 + t * 4);
    r0 = rv.x; r1 = rv.y; r2 = rv.z; r3 = rv.w;
  } else {
    bf16x4 rb = *(const bf16x4*)(resb + row * 1024 + t * 4);
    r0 = (float)rb[0]; r1 = (float)rb[1]; r2 = (float)rb[2]; r3 = (float)rb[3];
  }
  const float x0 = (float)av[0] + r0, x1 = (float)av[1] + r1,
              x2 = (float)av[2] + r2, x3 = (float)av[3] + r3;
  float s = x0 + x1 + x2 + x3;
  float q = x0 * x0 + x1 * x1 + x2 * x2 + x3 * x3;
#pragma unroll
  for (int o = 32; o > 0; o >>= 1) {
    s += __shfl_down(s, o, 64);
    q += __shfl_down(q, o, 64);
  }
  if ((t & 63) == 0) {
    rs[t >> 6] = s;
    rq[t >> 6] = q;
  }
  __syncthreads();
  s = rs[0] + rs[1] + rs[2] + rs[3];
  q = rq[0] + rq[1] + rq[2] + rq[3];
  const float mean = s * (1.0f / 1024.0f);
  const float var = q * (1.0f / 1024.0f) - mean * mean;
  const float inv = rsqrtf(var + 1e-5f);
  float4 gv = *(const float4*)(gamma + t * 4);
  float4 bv = *(const float4*)(beta + t * 4);
  const float o0 = (x0 - mean) * inv * gv.x + bv.x;
  const float o1 = (x1 - mean) * inv * gv.y + bv.y;
  const float o2 = (x2 - mean) * inv * gv.z + bv.z;
  const float o3 = (x3 - mean) * inv * gv.w + bv.w;
  if (outf) *(float4*)(outf + row * 1024 + t * 4) = make_float4(o0, o1, o2, o3);
  if (outb) {
    bf16_t* ob = outb + row * 1024 + t * 4;
    ob[0] = (bf16_t)o0;
    ob[1] = (bf16_t)o1;
    ob[2] = (bf16_t)o2;
    ob[3] = (bf16_t)o3;
  }
}

extern "C" void kernel_launch(void* const* d_in, const int* in_sizes, int n_in,
                              void* d_out, int out_size, void* d_ws,
                              size_t ws_size, hipStream_t stream) {
  (void)in_sizes;
  (void)n_in;
  (void)out_size;
  const float* x = (const float*)d_in[0];
  const float* Wq = (const float*)d_in[1];
  const float* Wk = (const float*)d_in[2];
  const float* Wv = (const float*)d_in[3];
  const float* Wo = (const float*)d_in[4];
  const float* bo = (const float*)d_in[5];
  const float* w1 = (const float*)d_in[6];
  const float* b1 = (const float*)d_in[7];
  const float* w2 = (const float*)d_in[8];
  const float* b2 = (const float*)d_in[9];
  const float* w3 = (const float*)d_in[10];
  const float* b3 = (const float*)d_in[11];
  const float* w4 = (const float*)d_in[12];
  const float* b4 = (const float*)d_in[13];
  const float* g1 = (const float*)d_in[14];
  const float* be1 = (const float*)d_in[15];
  const float* g2 = (const float*)d_in[16];
  const float* be2 = (const float*)d_in[17];
  float* out = (float*)d_out;

  const size_t MB = 1024ull * 1024ull;
  char* base = (char*)d_ws;
  const long long SD = (long long)NS * ND;  // 2M elements

  // ---- attention arena (peak 120 MB) ----
  bf16_t* xb = (bf16_t*)(base + 0 * MB);        // [0,16)
  bf16_t* WqTg = (bf16_t*)(base + 16 * MB);     // [16,18)
  bf16_t* WkTg = (bf16_t*)(base + 18 * MB);     // [18,20)
  bf16_t* WvTg = (bf16_t*)(base + 20 * MB);     // [20,22)
  bf16_t* WoTg = (bf16_t*)(base + 22 * MB);     // [22,24)
  bf16_t* attnprojb = (bf16_t*)(base + 24 * MB);// [24,40)
  bf16_t* qs = (bf16_t*)(base + 40 * MB);       // [40,56)  (later: PV out)
  bf16_t* ks = (bf16_t*)(base + 56 * MB);       // [56,72)
  bf16_t* vts = (bf16_t*)(base + 72 * MB);      // [72,88)
  bf16_t* scs = (bf16_t*)(base + 88 * MB);      // [88,120) 4 slices
  bf16_t* pvout = qs;                           // qs dead after scores
  // ---- FFN arena ----
  bf16_t* zbuf = (bf16_t*)(base + 0 * MB);      // [0,16)  (xb dead)
  bf16_t* y4b = (bf16_t*)(base + 16 * MB);      // [16,32)
  bf16_t* w1T = (bf16_t*)(base + 32 * MB);      // [32,40)
  bf16_t* w4T = (bf16_t*)(base + 40 * MB);      // [40,48)
  const int big = ws_size >= 180 * MB;
  // compact: shared 32 MB slot for w2T/w3T; 4 chunks of 2048 rows
  // big:     resident w2T/w3T; 2 chunks of 4096 rows; peak 176 MB
  bf16_t* w2T = (bf16_t*)(base + 48 * MB);
  bf16_t* w3T = big ? (bf16_t*)(base + 80 * MB) : w2T;
  bf16_t* y1c = big ? (bf16_t*)(base + 112 * MB) : (bf16_t*)(base + 80 * MB);
  bf16_t* y2c = big ? (bf16_t*)(base + 144 * MB) : (bf16_t*)(base + 96 * MB);

  // ---- prep: x -> bf16 ----
  f32_to_bf16<<<dim3(2048), dim3(256), 0, stream>>>(x, xb,
                                                    (long long)NTOK * ND);

  // ---- attention: per head, all batches z-fused; Wo accumulated ----
  for (int h = 0; h < NH; ++h) {
    transpose_to_bf16<<<dim3(32, 32, 1), dim3(256), 0, stream>>>(
        Wq + (long long)h * ND * ND, WqTg, ND, ND, 0, 0);
    transpose_to_bf16<<<dim3(32, 32, 1), dim3(256), 0, stream>>>(
        Wk + (long long)h * ND * ND, WkTg, ND, ND, 0, 0);
    transpose_to_bf16<<<dim3(32, 32, 1), dim3(256), 0, stream>>>(
        Wv + (long long)h * ND * ND, WvTg, ND, ND, 0, 0);
    transpose_to_bf16<<<dim3(32, 32, 1), dim3(256), 0, stream>>>(
        Wo + (long long)h * ND * ND, WoTg, ND, ND, 0, 0);

    // fused Q+K: z = (proj, batch): zo picks Wq/Wk and qs/ks, zr picks batch
    gemm_bt<true, false><<<dim3(8, 16, 8), dim3(256), 0, stream>>>(
        xb, ND, WqTg, ND, qs, ND, ND, 1.0f, nullptr, 0, 0, NB, 0LL, SD,
        (long long)ND * ND, 0LL, 4 * SD, SD);
    // V^T: z = batch
    gemm_bt<true, true><<<dim3(8, 16, NB), dim3(256), 0, stream>>>(
        xb, ND, WvTg, ND, vts, NS, ND, 1.0f, nullptr, 0, 0, NB, 0LL, SD, 0LL,
        0LL, 0LL, SD);
    // scores = q k^T / 32 : z = batch
    gemm_bt<true, false><<<dim3(16, 16, NB), dim3(256), 0, stream>>>(
        qs, ND, ks, ND, scs, NS, ND, 0.03125f, nullptr, 0, 0, NB, 0LL, SD, 0LL,
        SD, 0LL, (long long)NS * NS);
    softmax2048<<<dim3(NB * NS), dim3(256), 0, stream>>>(scs);
    // PV : z = batch, out contiguous [bi][s][e] (reuses qs region)
    gemm_bt<true, false><<<dim3(8, 16, NB), dim3(256), 0, stream>>>(
        scs, NS, vts, NS, pvout, ND, NS, 1.0f, nullptr, 0, 0, NB, 0LL,
        (long long)NS * NS, 0LL, SD, 0LL, SD);
    // attnprojb (+)= pvout @ WoTg^T : M=8192, K=1024 (bias at h==0)
    gemm_bt<true, false><<<dim3(8, 64, 1), dim3(256), 0, stream>>>(
        pvout, ND, WoTg, ND, attnprojb, ND, ND, 1.0f, bo, 0, (h > 0) ? 1 : 0,
        1, 0LL, 0LL, 0LL, 0LL, 0LL, 0LL);
  }

  // z = LN(x + attnproj)  (bf16 out; overwrites xb region)
  add_res_ln<<<dim3(NTOK), dim3(256), 0, stream>>>(attnprojb, x, nullptr, g1,
                                                   be1, nullptr, zbuf);

  // ---- FFN ----
  transpose_to_bf16<<<dim3(128, 32, 1), dim3(256), 0, stream>>>(w1, w1T, ND,
                                                                NHID, 0, 0);
  transpose_to_bf16<<<dim3(32, 128, 1), dim3(256), 0, stream>>>(w4, w4T, NHID,
                                                                ND, 0, 0);
  if (big) {
    transpose_to_bf16<<<dim3(128, 128, 1), dim3(256), 0, stream>>>(
        w2, w2T, NHID, NHID, 0, 0);
    transpose_to_bf16<<<dim3(128, 128, 1), dim3(256), 0, stream>>>(
        w3, w3T, NHID, NHID, 0, 0);
  }
  const int nchunk = big ? 2 : 4;
  const int crows = NTOK / nchunk;  // 4096 or 2048
  const int cgy = crows / 128;      // 32 or 16
  for (int c = 0; c < nchunk; ++c) {
    const bf16_t* zrow = zbuf + (long long)c * crows * ND;
    // y1c = relu(z w1 + b1) : N=4096, K=1024
    gemm_bt<true, false><<<dim3(32, cgy, 1), dim3(256), 0, stream>>>(
        zrow, ND, w1T, ND, y1c, NHID, ND, 1.0f, b1, 1, 0, 1, 0LL, 0LL, 0LL,
        0LL, 0LL, 0LL);
    if (!big)
      transpose_to_bf16<<<dim3(128, 128, 1), dim3(256), 0, stream>>>(
          w2, w2T, NHID, NHID, 0, 0);
    // y2c = relu(y1c w2 + b2) : K=4096
    gemm_bt<true, false><<<dim3(32, cgy, 1), dim3(256), 0, stream>>>(
        y1c, NHID, w2T, NHID, y2c, NHID, NHID, 1.0f, b2, 1, 0, 1, 0LL, 0LL,
        0LL, 0LL, 0LL, 0LL);
    if (!big)
      transpose_to_bf16<<<dim3(128, 128, 1), dim3(256), 0, stream>>>(
          w3, w3T, NHID, NHID, 0, 0);
    // y3c = relu(y2c w3 + b3) : K=4096 (aliases y1c)
    gemm_bt<true, false><<<dim3(32, cgy, 1), dim3(256), 0, stream>>>(
        y2c, NHID, w3T, NHID, y1c, NHID, NHID, 1.0f, b3, 1, 0, 1, 0LL, 0LL,
        0LL, 0LL, 0LL, 0LL);
    // y4 = y3c w4 + b4 : N=1024, K=4096, bf16 out
    gemm_bt<true, false><<<dim3(8, cgy, 1), dim3(256), 0, stream>>>(
        y1c, NHID, w4T, NHID, y4b + (long long)c * crows * ND, ND, NHID, 1.0f,
        b4, 0, 0, 1, 0LL, 0LL, 0LL, 0LL, 0LL, 0LL);
  }

  // out = LN(z + y4)
  add_res_ln<<<dim3(NTOK), dim3(256), 0, stream>>>(y4b, nullptr, zbuf, g2, be2,
                                                   out, nullptr);
}